// Round 1
// baseline (353.759 us; speedup 1.0000x reference)
//
#include <hip/hip_runtime.h>
#include <hip/hip_bf16.h>

// InteractionBlock: B=16,N=192,H=128,F=128,G=50
//   fw  = softplus(rbf@W1+b1)@W2+b2          [B,N,N,F]   (never materialized)
//   nf  = features@Wf+bf                      [B,N,F]
//   agg = sum_j mask[b,i,j]*fw[b,i,j,:]*nf[b,j,:]
//   out = features + softplus(agg@Wo1+bo1)@Wo2+bo2
//
// Strategy: one block per (b,i). GEMM1+softplus -> LDS (bf16), GEMM2 + fused
// masked reduction, all via mfma_f32_16x16x32_bf16. Weights pre-transposed to
// bf16 [n][k] in ws so B-frags are single 16B loads. Runtime dtype detection
// (bf16 vs fp32 harness) via bit-pattern probe -> flag in ws.

typedef __bf16 bf16_t;
typedef __bf16 bf16x8 __attribute__((ext_vector_type(8)));
typedef float  f32x4  __attribute__((ext_vector_type(4)));

constexpr int kB = 16, kN = 192, kH = 128, kF = 128, kG = 50;
constexpr int kRows = kB * kN;        // 3072
constexpr int kHsPitch = 136;         // bf16 elems; 68 words -> uniform 8 words/bank for b128 frag reads

__device__ __forceinline__ float ldf(const void* p, int i, bool bfm) {
  return bfm ? (float)((const bf16_t*)p)[i] : ((const float*)p)[i];
}

__device__ __forceinline__ float softplus_f(float x) {
  // fast softplus; result is rounded to bf16 downstream, so __expf/__logf precision is ample
  float t = __logf(1.f + __expf(fminf(x, 20.f)));
  return x > 20.f ? x : t;
}

// ---- dtype detector: flag=1 if inputs are packed bf16, 0 if fp32 ----
__global__ __launch_bounds__(256) void detect_kernel(const unsigned int* __restrict__ rbf_w,
                                                     int* __restrict__ flag) {
  __shared__ int c_hi, c_zero;
  const int t = threadIdx.x;
  if (t == 0) { c_hi = 0; c_zero = 0; }
  __syncthreads();
  unsigned int w = rbf_w[(size_t)t * 40003u];   // in-bounds for both dtypes (>=14.7M words)
  unsigned int lo = w & 0xFFFFu;                // low half: bf16 elem (packed) or fp32 low mantissa
  if (((lo >> 7) & 0xFFu) >= 128u) atomicAdd(&c_hi, 1);   // |bf16| >= 2: impossible for rbf in [0,1)
  if (lo == 0u) atomicAdd(&c_zero, 1);                     // bf16-rounded-but-fp32-stored
  __syncthreads();
  if (t == 0) *flag = (c_hi == 0 && c_zero < 200) ? 1 : 0;
}

// ---- transpose W1 (pad G 50->64) and W2 into bf16 [n][k] ----
__global__ __launch_bounds__(256) void prep_kernel(const void* __restrict__ W1,
                                                   const void* __restrict__ W2,
                                                   const int* __restrict__ flag,
                                                   bf16_t* __restrict__ w1t,
                                                   bf16_t* __restrict__ w2t) {
  const bool bfm = *flag != 0;
  int idx = blockIdx.x * 256 + threadIdx.x;
  if (idx < 128 * 64) {
    int n = idx >> 6, k = idx & 63;
    w1t[idx] = (k < kG) ? (bf16_t)ldf(W1, k * kF + n, bfm) : (bf16_t)0.f;
  } else if (idx < 128 * 64 + 128 * 128) {
    int id2 = idx - 128 * 64;
    int n = id2 >> 7, k = id2 & 127;
    w2t[id2] = (bf16_t)ldf(W2, k * kF + n, bfm);
  }
}

// ---- nf = features @ Wf + bf  (fp32 result in ws) ----
__global__ __launch_bounds__(128) void nf_kernel(const void* __restrict__ features,
                                                 const void* __restrict__ Wf,
                                                 const void* __restrict__ bfv,
                                                 const int* __restrict__ flag,
                                                 float* __restrict__ nf) {
  const bool bfm = *flag != 0;
  int row = blockIdx.x, f = threadIdx.x;
  __shared__ float s_x[kH];
  s_x[f] = ldf(features, row * kH + f, bfm);
  __syncthreads();
  float acc = ldf(bfv, f, bfm);
#pragma unroll 8
  for (int k = 0; k < kH; ++k) acc = fmaf(s_x[k], ldf(Wf, k * kF + f, bfm), acc);
  nf[row * kF + f] = acc;
}

// ---- main: per (b,i): GEMM1 -> softplus -> LDS -> GEMM2 -> masked reduce ----
__global__ __launch_bounds__(256) void main_kernel(
    const void* __restrict__ rbf, const int* __restrict__ nmask,
    const void* __restrict__ b1p, const void* __restrict__ b2p,
    const bf16_t* __restrict__ w1t, const bf16_t* __restrict__ w2t,
    const float* __restrict__ nf, const int* __restrict__ flag,
    float* __restrict__ agg) {
  __shared__ bf16_t s_hs[kN * kHsPitch];   // 52224 B
  __shared__ float  s_mask[kN];
  __shared__ float  s_agg[kF];

  const bool bfm = *flag != 0;
  const int bi = blockIdx.x;
  const int b  = bi / kN;
  const int t  = threadIdx.x;
  const int wave = t >> 6, lane = t & 63;
  const int n16 = lane & 15, q = lane >> 4;
  const int m0w = wave * 48;               // this wave's 48 rows (3 M-tiles)

  for (int idx = t; idx < kN; idx += 256) s_mask[idx] = (float)nmask[bi * kN + idx];
  if (t < kF) s_agg[t] = 0.f;

  f32x4 acc[3][8];
#pragma unroll
  for (int mt = 0; mt < 3; ++mt)
#pragma unroll
    for (int nt = 0; nt < 8; ++nt)
#pragma unroll
      for (int r = 0; r < 4; ++r) acc[mt][nt][r] = 0.f;

  // ---- GEMM1: H[192,128] = rbf[192, 50->64] @ W1 ----
  const size_t rbase = (size_t)bi * (kN * kG);
#pragma unroll
  for (int ks = 0; ks < 2; ++ks) {
    bf16x8 afr[3];
#pragma unroll
    for (int mt = 0; mt < 3; ++mt) {
      const int j  = m0w + mt * 16 + n16;          // A[m = lane&15]
      const int kb = ks * 32 + q * 8;              // A[k = quad*8 + i]
      if (bfm) {
        const bf16_t* rp = (const bf16_t*)rbf + rbase + (size_t)j * kG;
#pragma unroll
        for (int i = 0; i < 8; ++i) {
          int k = kb + i;
          afr[mt][i] = (k < kG) ? rp[k] : (bf16_t)0.f;
        }
      } else {
        const float* rp = (const float*)rbf + rbase + (size_t)j * kG;
#pragma unroll
        for (int i = 0; i < 8; ++i) {
          int k = kb + i;
          afr[mt][i] = (bf16_t)((k < kG) ? rp[k] : 0.f);
        }
      }
    }
#pragma unroll
    for (int nt = 0; nt < 8; ++nt) {
      bf16x8 bfr = *(const bf16x8*)(w1t + (nt * 16 + n16) * 64 + ks * 32 + q * 8);
#pragma unroll
      for (int mt = 0; mt < 3; ++mt)
        acc[mt][nt] = __builtin_amdgcn_mfma_f32_16x16x32_bf16(afr[mt], bfr, acc[mt][nt], 0, 0, 0);
    }
  }

  // bias + softplus -> s_hs (bf16). C/D layout: col = lane&15, row = q*4 + r.
#pragma unroll
  for (int nt = 0; nt < 8; ++nt) {
    const int col = nt * 16 + n16;
    const float bb = ldf(b1p, col, bfm);
#pragma unroll
    for (int mt = 0; mt < 3; ++mt) {
      const int jb = m0w + mt * 16 + q * 4;
#pragma unroll
      for (int r = 0; r < 4; ++r)
        s_hs[(jb + r) * kHsPitch + col] = (bf16_t)softplus_f(acc[mt][nt][r] + bb);
    }
  }
  __syncthreads();

  // ---- GEMM2: FW = Hs[192,128] @ W2[128,128] ----
#pragma unroll
  for (int mt = 0; mt < 3; ++mt)
#pragma unroll
    for (int nt = 0; nt < 8; ++nt)
#pragma unroll
      for (int r = 0; r < 4; ++r) acc[mt][nt][r] = 0.f;

#pragma unroll
  for (int ks = 0; ks < 4; ++ks) {
    bf16x8 afr[3];
#pragma unroll
    for (int mt = 0; mt < 3; ++mt)
      afr[mt] = *(const bf16x8*)(s_hs + (m0w + mt * 16 + n16) * kHsPitch + ks * 32 + q * 8);
#pragma unroll
    for (int nt = 0; nt < 8; ++nt) {
      bf16x8 bfr = *(const bf16x8*)(w2t + (nt * 16 + n16) * 128 + ks * 32 + q * 8);
#pragma unroll
      for (int mt = 0; mt < 3; ++mt)
        acc[mt][nt] = __builtin_amdgcn_mfma_f32_16x16x32_bf16(afr[mt], bfr, acc[mt][nt], 0, 0, 0);
    }
  }

  // ---- epilogue: p = sum_rows mask * (fw + b2) * nf ; reduce into s_agg ----
#pragma unroll
  for (int nt = 0; nt < 8; ++nt) {
    const int f = nt * 16 + n16;
    const float b2v = ldf(b2p, f, bfm);
    float p = 0.f;
#pragma unroll
    for (int mt = 0; mt < 3; ++mt) {
      const int jb = m0w + mt * 16 + q * 4;
#pragma unroll
      for (int r = 0; r < 4; ++r) {
        const int j = jb + r;
        const float m   = s_mask[j];
        const float nfv = nf[((size_t)b * kN + j) * kF + f];
        p = fmaf(m * (acc[mt][nt][r] + b2v), nfv, p);
      }
    }
    atomicAdd(&s_agg[f], p);
  }
  __syncthreads();
  if (t < kF) agg[(size_t)bi * kF + t] = s_agg[t];
}

// ---- out = features + softplus(agg@Wo1+bo1)@Wo2+bo2 ----
__global__ __launch_bounds__(128) void out_kernel(
    const float* __restrict__ agg, const void* __restrict__ features,
    const void* __restrict__ Wo1, const void* __restrict__ bo1,
    const void* __restrict__ Wo2, const void* __restrict__ bo2,
    const int* __restrict__ flag, void* __restrict__ out) {
  const bool bfm = *flag != 0;
  int row = blockIdx.x, h = threadIdx.x;
  __shared__ float s_a[kF], s_t[kH];
  s_a[h] = agg[row * kF + h];
  __syncthreads();
  float a1 = ldf(bo1, h, bfm);
#pragma unroll 8
  for (int k = 0; k < kF; ++k) a1 = fmaf(s_a[k], ldf(Wo1, k * kH + h, bfm), a1);
  s_t[h] = softplus_f(a1);
  __syncthreads();
  float a2 = ldf(bo2, h, bfm);
#pragma unroll 8
  for (int k = 0; k < kH; ++k) a2 = fmaf(s_t[k], ldf(Wo2, k * kH + h, bfm), a2);
  float res = ldf(features, row * kH + h, bfm) + a2;
  if (bfm) ((bf16_t*)out)[row * kH + h] = (bf16_t)res;
  else     ((float*)out)[row * kH + h]  = res;
}

extern "C" void kernel_launch(void* const* d_in, const int* in_sizes, int n_in,
                              void* d_out, int out_size, void* d_ws, size_t ws_size,
                              hipStream_t stream) {
  const void* features = d_in[0];
  const void* rbf      = d_in[1];
  const int*  nmask    = (const int*)d_in[2];
  const void* W1  = d_in[3];
  const void* b1  = d_in[4];
  const void* W2  = d_in[5];
  const void* b2  = d_in[6];
  const void* Wf  = d_in[7];
  const void* bfv = d_in[8];
  const void* Wo1 = d_in[9];
  const void* bo1 = d_in[10];
  const void* Wo2 = d_in[11];
  const void* bo2 = d_in[12];

  char* ws = (char*)d_ws;
  float*  nf   = (float*)ws;                   // 3072*128 f32 = 1,572,864 B
  float*  agg  = (float*)(ws + 1572864);       // 1,572,864 B
  bf16_t* w1t  = (bf16_t*)(ws + 3145728);      // 128*64 bf16 = 16,384 B
  bf16_t* w2t  = (bf16_t*)(ws + 3162112);      // 128*128 bf16 = 32,768 B
  int*    flag = (int*)(ws + 3194880);         // 4 B

  detect_kernel<<<1, 256, 0, stream>>>((const unsigned int*)rbf, flag);
  prep_kernel<<<96, 256, 0, stream>>>(W1, W2, flag, w1t, w2t);
  nf_kernel<<<kRows, 128, 0, stream>>>(features, Wf, bfv, flag, nf);
  main_kernel<<<kRows, 256, 0, stream>>>(rbf, nmask, b1, b2, w1t, w2t, nf, flag, agg);
  out_kernel<<<kRows, 128, 0, stream>>>(agg, features, Wo1, bo1, Wo2, bo2, flag, d_out);
}